// Round 12
// baseline (268.725 us; speedup 1.0000x reference)
//
#include <hip/hip_runtime.h>
#include <hip/hip_bf16.h>

// RGCN regression: N=50000, E=800000, R=8, C=H=128.
// Round 12: TRANSFORM-THEN-AGGREGATE. mean_e(x)@W == mean_e(x@W), so:
//   gemm_t : t[N,1152] = feat @ [root|W0..W7]^T  (dense, A = 12.8MB feat only,
//            K=128 one-shot, bias folded into m<128 slice)
//   finish : per node, gather-mean relation slices of t (R5's proven walk),
//            shfl_xor(8/16/32) cross-relation sum, + base t[n,0:128], relu ->
//            h1 bf16  (layer 1)  or fused head dot -> out  (layer 2).
// Kills the 102MB agg intermediate (100MB write + ~64MB re-read per layer).
// Sort prep (R6) and cvt unchanged.

constexpr int NN = 50000;
constexpr int EE = 800000;
constexpr int NB = NN * 8;            // 400000 (dst,rel) buckets
constexpr int NCB = (NN + 255) >> 8;  // 196 coarse buckets
constexpr int EPB = 8192;             // edges per partition block
constexpr int PBLK = (EE + EPB - 1) / EPB;   // 98
constexpr int NSB = 2048;             // sub-buckets per coarse bucket

typedef __attribute__((ext_vector_type(8))) short bf16x8;
typedef __attribute__((ext_vector_type(16))) float f32x16;
typedef __attribute__((address_space(3))) uint32_t lds_u32;
typedef __attribute__((address_space(1))) const uint32_t glb_u32;

static __device__ __forceinline__ ushort f2bf(float f) {
    uint u = __float_as_uint(f);
    uint r = (u + 0x7fffu + ((u >> 16) & 1u)) >> 16;   // RTNE
    return (ushort)r;
}
static __device__ __forceinline__ float bflo(uint v) { return __uint_as_float(v << 16); }
static __device__ __forceinline__ float bfhi(uint v) { return __uint_as_float(v & 0xffff0000u); }

static __device__ __forceinline__ void stage16(const void* g, void* lds) {
    __builtin_amdgcn_global_load_lds((glb_u32*)g, (lds_u32*)lds, 16, 0, 0);
}

// ---------------- P1: coarse histogram (dst>>8), LDS-aggregated ----------------
__global__ __launch_bounds__(1024) void chist_kernel(const int* __restrict__ dst,
                                                     int* __restrict__ ghist) {
    __shared__ int h[NCB];
    const int t = threadIdx.x;
    for (int i = t; i < NCB; i += 1024) h[i] = 0;
    __syncthreads();
    const int e0 = blockIdx.x * EPB + t;
#pragma unroll
    for (int jj = 0; jj < 8; ++jj) {
        const int e = e0 + jj * 1024;
        if (e < EE) atomicAdd(&h[dst[e] >> 8], 1);
    }
    __syncthreads();
    for (int i = t; i < NCB; i += 1024)
        if (h[i]) atomicAdd(&ghist[i], h[i]);
}

// ---------------- P2: scan 196 coarse totals ----------------
__global__ __launch_bounds__(256) void cscan_kernel(const int* __restrict__ ghist,
                                                    int* __restrict__ gstart,
                                                    int* __restrict__ gcur) {
    __shared__ int sm[256];
    const int t = threadIdx.x;
    const int v = (t < NCB) ? ghist[t] : 0;
    sm[t] = v;
    __syncthreads();
    for (int d = 1; d < 256; d <<= 1) {
        int u = (t >= d) ? sm[t - d] : 0;
        __syncthreads();
        sm[t] += u;
        __syncthreads();
    }
    const int excl = sm[t] - v;
    if (t < NCB) { gstart[t] = excl; gcur[t] = excl; }
    if (t == NCB - 1) gstart[NCB] = excl + v;   // == EE
}

// ---------------- P3: coarse partition, block-reserved ranges ----------------
// packed = (dlow<<19) | (et<<16) | src
__global__ __launch_bounds__(1024) void cpart_kernel(const int* __restrict__ src,
                                                     const int* __restrict__ dst,
                                                     const int* __restrict__ et,
                                                     int* __restrict__ gcur,
                                                     uint* __restrict__ packed) {
    __shared__ int h[NCB];
    const int t = threadIdx.x;
    for (int i = t; i < NCB; i += 1024) h[i] = 0;
    __syncthreads();
    const int e0 = blockIdx.x * EPB + t;
    int myb[8]; uint mydat[8];
#pragma unroll
    for (int jj = 0; jj < 8; ++jj) {
        const int e = e0 + jj * 1024;
        if (e < EE) {
            const int d = dst[e];
            myb[jj] = d >> 8;
            mydat[jj] = (uint)src[e] | ((uint)et[e] << 16) | ((uint)(d & 255) << 19);
            atomicAdd(&h[myb[jj]], 1);
        } else myb[jj] = -1;
    }
    __syncthreads();
    for (int i = t; i < NCB; i += 1024)
        h[i] = h[i] ? atomicAdd(&gcur[i], h[i]) : 0;   // h becomes running cursor
    __syncthreads();
#pragma unroll
    for (int jj = 0; jj < 8; ++jj) {
        if (myb[jj] >= 0) {
            const int pos = atomicAdd(&h[myb[jj]], 1);
            packed[pos] = mydat[jj];
        }
    }
}

// ---------------- P4: per-coarse-bucket fine sort -> off[] + srcs[] ----------------
__global__ __launch_bounds__(1024) void fsort_kernel(const int* __restrict__ gstart,
                                                     const uint* __restrict__ packed,
                                                     int* __restrict__ off,
                                                     int* __restrict__ srcs) {
    __shared__ int hist[NSB];
    __shared__ int scn[NSB];
    __shared__ int h2[1024];
    const int b = blockIdx.x;
    const int t = threadIdx.x;
    const int s = gstart[b], e = gstart[b + 1];

    for (int i = t; i < NSB; i += 1024) hist[i] = 0;
    __syncthreads();
    for (int i = s + t; i < e; i += 1024)
        atomicAdd(&hist[(packed[i] >> 16) & 0x7FF], 1);
    __syncthreads();
    const int a0 = hist[2 * t], a1 = hist[2 * t + 1];
    h2[t] = a0 + a1;
    __syncthreads();
    for (int d = 1; d < 1024; d <<= 1) {
        int u = (t >= d) ? h2[t - d] : 0;
        __syncthreads();
        h2[t] += u;
        __syncthreads();
    }
    const int base = h2[t] - (a0 + a1);
    scn[2 * t] = base;
    scn[2 * t + 1] = base + a0;
    __syncthreads();
    const int gsubbase = b << 11;
    for (int i = t; i < NSB; i += 1024) {
        const int g = gsubbase + i;
        if (g < NB) off[g] = s + scn[i];
    }
    if (b == NCB - 1 && t == 0) off[NB] = EE;
    __syncthreads();
    for (int i = s + t; i < e; i += 1024) {
        const uint k = packed[i];
        const int pos = atomicAdd(&scn[(k >> 16) & 0x7FF], 1);
        srcs[s + pos] = (int)(k & 0xFFFF);
    }
}

// ---------------- x fp32 -> bf16 ----------------
__global__ __launch_bounds__(256) void cvt_x_kernel(const float* __restrict__ x,
                                                    ushort* __restrict__ xb) {
    const int tid = blockIdx.x * blockDim.x + threadIdx.x;
    const size_t i = (size_t)tid * 8;
    const float4 v0 = *reinterpret_cast<const float4*>(x + i);
    const float4 v1 = *reinterpret_cast<const float4*>(x + i + 4);
    uint4 o;
    o.x = (uint)f2bf(v0.x) | ((uint)f2bf(v0.y) << 16);
    o.y = (uint)f2bf(v0.z) | ((uint)f2bf(v0.w) << 16);
    o.z = (uint)f2bf(v1.x) | ((uint)f2bf(v1.y) << 16);
    o.w = (uint)f2bf(v1.z) | ((uint)f2bf(v1.w) << 16);
    *reinterpret_cast<uint4*>(xb + i) = o;
}

// ---------------- weights -> Bt[m][k] bf16, m = [root(128) | W0..W7(1024)] ----------------
// Bt[m*128+k] : m<128 -> root[k][m] ; m>=128 -> W[r][k][h], r=(m-128)>>7, h=(m-128)&127
__global__ __launch_bounds__(128) void prep_w_kernel(const float* __restrict__ root1,
                                                     const float* __restrict__ W1,
                                                     const float* __restrict__ root2,
                                                     const float* __restrict__ W2,
                                                     ushort* __restrict__ Bt1,
                                                     ushort* __restrict__ Bt2) {
    const float* root = blockIdx.y ? root2 : root1;
    const float* W    = blockIdx.y ? W2 : W1;
    ushort* Bt        = blockIdx.y ? Bt2 : Bt1;
    const int m = blockIdx.x;                       // 0..1151
    const int k = threadIdx.x;                      // 0..127
    float v;
    if (m < 128) v = root[(size_t)k * 128 + m];
    else {
        const int r = (m - 128) >> 7, h = (m - 128) & 127;
        v = W[(size_t)r * 16384 + (size_t)k * 128 + h];
    }
    Bt[(size_t)m * 128 + k] = f2bf(v);
}

// ---------------- gemm_t: t[N,1152] = feat @ Bt^T (+bias on m<128) ----------------
// Block: 4 waves (2x2), tile 64(M rows) x 128(cols m), K=128 single-shot.
// LDS: A 64x256B (16K) | B 128x256B (32K), chunk swizzle ^(row&7) both sides.
__global__ __launch_bounds__(256) void gemm_t(const ushort* __restrict__ feat,
                                              const ushort* __restrict__ Bt,
                                              const float* __restrict__ bias,
                                              ushort* __restrict__ tout) {
    __shared__ __align__(16) uint8_t smem[49152];   // A[0,16K) | B[16K,48K)
    const int t = threadIdx.x;
    const int lane = t & 63;
    const int w = t >> 6;
    const int wr = w >> 1, wc = w & 1;
    const int n0 = blockIdx.y * 64;
    const int c0 = blockIdx.x * 128;
    const int l31 = lane & 31;
    const int lhalf = lane >> 5;

    f32x16 acc0, acc1;
#pragma unroll
    for (int r = 0; r < 16; ++r) { acc0[r] = 0.f; acc1[r] = 0.f; }

    // fragment read constants (256B rows, chunk swizzle ^(row&7))
    const int rA = wr * 32 + l31;
    const int aoff = rA * 256, aswz = (rA & 7) << 4;
    const int mB0 = wc * 64 + l31, mB1 = mB0 + 32;
    const int boff0 = 16384 + mB0 * 256, bswz0 = (mB0 & 7) << 4;
    const int boff1 = 16384 + mB1 * 256, bswz1 = (mB1 & 7) << 4;
    const int ckb = lhalf << 4;

    // staging: instr covers 4 rows x 256B; lane row = lane>>4, chunk = lane&15
    const int srow = lane >> 4, schunk = lane & 15;
    const uint8_t* feat8 = (const uint8_t*)feat;
    const uint8_t* Bt8   = (const uint8_t*)Bt;

    // A: 16 instrs total, wave w does {4w..4w+3}
#pragma unroll
    for (int jj = 0; jj < 4; ++jj) {
        const int ia = 4 * w + jj;
        const int lr = ia * 4 + srow;                 // 0..63
        const int gr = min(n0 + lr, NN - 1);
        stage16(feat8 + (size_t)gr * 256 + ((schunk ^ (lr & 7)) << 4),
                smem + ia * 1024);
    }
    // B: 32 instrs total, wave w does {8w..8w+7}
#pragma unroll
    for (int jj = 0; jj < 8; ++jj) {
        const int ib = 8 * w + jj;
        const int mloc = ib * 4 + srow;               // 0..127
        stage16(Bt8 + (size_t)(c0 + mloc) * 256 + ((schunk ^ (mloc & 7)) << 4),
                smem + 16384 + ib * 1024);
    }
    __syncthreads();                                  // vmcnt(0) drain

#pragma unroll
    for (int kb = 0; kb < 8; ++kb) {
        const int cb = kb * 32 + ckb;
        const bf16x8 af = *reinterpret_cast<const bf16x8*>(smem + aoff  + (cb ^ aswz));
        const bf16x8 b0 = *reinterpret_cast<const bf16x8*>(smem + boff0 + (cb ^ bswz0));
        const bf16x8 b1 = *reinterpret_cast<const bf16x8*>(smem + boff1 + (cb ^ bswz1));
        acc0 = __builtin_amdgcn_mfma_f32_32x32x16_bf16(af, b0, acc0, 0, 0, 0);
        acc1 = __builtin_amdgcn_mfma_f32_32x32x16_bf16(af, b1, acc1, 0, 0, 0);
    }

    // epilogue: 32x32 C/D: col=lane&31, row=(reg&3)+8*(reg>>2)+4*lhalf
#pragma unroll
    for (int ni = 0; ni < 2; ++ni) {
        const int m = c0 + wc * 64 + ni * 32 + l31;
        const float bv = (m < 128) ? bias[m] : 0.f;   // fold bias into base slice
        const f32x16& a = ni ? acc1 : acc0;
#pragma unroll
        for (int reg = 0; reg < 16; ++reg) {
            const int row = n0 + wr * 32 + 4 * lhalf + (reg & 3) + 8 * (reg >> 2);
            if (row < NN)
                tout[(size_t)row * 1152 + m] = f2bf(a[reg] + bv);
        }
    }
}

// ---------------- finish: h[n] = relu(base + sum_r mean_r) ; optional head ----------------
// Wave per node. lane = g*8+j: group g walks relation-g's segment reading
// t[src, 128+g*128 + j*16 ..] (32B/lane); scale 1/cnt; shfl_xor 8/16/32 sums
// groups; + base t[n, j*16..] (bias pre-folded); relu.
// outp==nullptr: g==0 lanes write bf16 h. Else: fused head dot -> outp[n].
__global__ __launch_bounds__(256) void finish_kernel(const ushort* __restrict__ t,
                                                     const int* __restrict__ off,
                                                     const int* __restrict__ srcs,
                                                     const float* __restrict__ Wout,
                                                     const float* __restrict__ bout,
                                                     ushort* __restrict__ hout,
                                                     float* __restrict__ outp) {
    const int wid = (blockIdx.x * blockDim.x + threadIdx.x) >> 6;
    if (wid >= NN) return;
    const int lane = threadIdx.x & 63;
    const int g = lane >> 3;            // relation group 0..7
    const int j = lane & 7;             // 16-ushort chunk within 128-col slice

    const int s1 = off[wid * 8 + g + 1];
    int i = off[wid * 8 + g];
    const int cnt = s1 - i;

    float a[16];
#pragma unroll
    for (int k = 0; k < 16; ++k) a[k] = 0.f;

    const ushort* tg = t + 128 + g * 128 + (j << 4);   // relation-g slice base
    int p = (i < s1) ? srcs[i] : 0;
    while (__any(i < s1)) {
        const bool act = i < s1;
        const int pn = (i + 1 < s1) ? srcs[i + 1] : 0;   // prefetch next src
        if (act) {
            const uint4* rp = reinterpret_cast<const uint4*>(tg + (size_t)p * 1152);
            const uint4 v0 = rp[0], v1 = rp[1];
            a[0] += bflo(v0.x);  a[1] += bfhi(v0.x);
            a[2] += bflo(v0.y);  a[3] += bfhi(v0.y);
            a[4] += bflo(v0.z);  a[5] += bfhi(v0.z);
            a[6] += bflo(v0.w);  a[7] += bfhi(v0.w);
            a[8] += bflo(v1.x);  a[9] += bfhi(v1.x);
            a[10] += bflo(v1.y); a[11] += bfhi(v1.y);
            a[12] += bflo(v1.z); a[13] += bfhi(v1.z);
            a[14] += bflo(v1.w); a[15] += bfhi(v1.w);
        }
        p = pn;
        ++i;
    }

    const float inv = 1.0f / (float)max(cnt, 1);
#pragma unroll
    for (int k = 0; k < 16; ++k) a[k] *= inv;

    // cross-relation sum: lanes {g*8+j | g=0..7} share column chunk j
#pragma unroll
    for (int k = 0; k < 16; ++k) {
        a[k] += __shfl_xor(a[k], 8, 64);
        a[k] += __shfl_xor(a[k], 16, 64);
        a[k] += __shfl_xor(a[k], 32, 64);
    }

    // base (root term + bias, pre-folded in gemm_t) + relu
    const uint4* bp = reinterpret_cast<const uint4*>(t + (size_t)wid * 1152 + (j << 4));
    const uint4 b0 = bp[0], b1 = bp[1];
    float h[16];
    h[0] = bflo(b0.x);  h[1] = bfhi(b0.x);
    h[2] = bflo(b0.y);  h[3] = bfhi(b0.y);
    h[4] = bflo(b0.z);  h[5] = bfhi(b0.z);
    h[6] = bflo(b0.w);  h[7] = bfhi(b0.w);
    h[8] = bflo(b1.x);  h[9] = bfhi(b1.x);
    h[10] = bflo(b1.y); h[11] = bfhi(b1.y);
    h[12] = bflo(b1.z); h[13] = bfhi(b1.z);
    h[14] = bflo(b1.w); h[15] = bfhi(b1.w);
#pragma unroll
    for (int k = 0; k < 16; ++k) h[k] = fmaxf(h[k] + a[k], 0.f);

    if (outp == nullptr) {
        if (g == 0) {
            uint4 o0, o1;
            o0.x = (uint)f2bf(h[0])  | ((uint)f2bf(h[1])  << 16);
            o0.y = (uint)f2bf(h[2])  | ((uint)f2bf(h[3])  << 16);
            o0.z = (uint)f2bf(h[4])  | ((uint)f2bf(h[5])  << 16);
            o0.w = (uint)f2bf(h[6])  | ((uint)f2bf(h[7])  << 16);
            o1.x = (uint)f2bf(h[8])  | ((uint)f2bf(h[9])  << 16);
            o1.y = (uint)f2bf(h[10]) | ((uint)f2bf(h[11]) << 16);
            o1.z = (uint)f2bf(h[12]) | ((uint)f2bf(h[13]) << 16);
            o1.w = (uint)f2bf(h[14]) | ((uint)f2bf(h[15]) << 16);
            ushort* o = hout + (size_t)wid * 128 + (j << 4);
            reinterpret_cast<uint4*>(o)[0] = o0;
            reinterpret_cast<uint4*>(o)[1] = o1;
        }
    } else {
        // fused head: out[n] = h . Wout + bout
        const float4 w0 = *reinterpret_cast<const float4*>(Wout + j * 16);
        const float4 w1 = *reinterpret_cast<const float4*>(Wout + j * 16 + 4);
        const float4 w2 = *reinterpret_cast<const float4*>(Wout + j * 16 + 8);
        const float4 w3 = *reinterpret_cast<const float4*>(Wout + j * 16 + 12);
        const float wv[16] = { w0.x,w0.y,w0.z,w0.w, w1.x,w1.y,w1.z,w1.w,
                               w2.x,w2.y,w2.z,w2.w, w3.x,w3.y,w3.z,w3.w };
        float part = 0.f;
#pragma unroll
        for (int k = 0; k < 16; ++k) part = fmaf(h[k], wv[k], part);
        part += __shfl_xor(part, 1, 64);
        part += __shfl_xor(part, 2, 64);
        part += __shfl_xor(part, 4, 64);
        if (lane == 0) outp[wid] = part + bout[0];
    }
}

extern "C" void kernel_launch(void* const* d_in, const int* in_sizes, int n_in,
                              void* d_out, int out_size, void* d_ws, size_t ws_size,
                              hipStream_t stream) {
    const float* x     = (const float*)d_in[0];
    const int*   eidx  = (const int*)  d_in[1];
    const int*   etype = (const int*)  d_in[2];
    const float* W1    = (const float*)d_in[3];
    const float* root1 = (const float*)d_in[4];
    const float* b1    = (const float*)d_in[5];
    const float* W2    = (const float*)d_in[6];
    const float* root2 = (const float*)d_in[7];
    const float* b2    = (const float*)d_in[8];
    const float* Wout  = (const float*)d_in[9];
    const float* bout  = (const float*)d_in[10];
    float* out = (float*)d_out;

    const int* src = eidx;
    const int* dst = eidx + EE;

    char* ws = (char*)d_ws;
    size_t pos = 0;
    auto take = [&](size_t bytes) {
        char* p = ws + pos;
        pos = (pos + bytes + 255) & ~(size_t)255;
        return p;
    };
    int*    ghist  = (int*)   take((size_t)NCB * 4);
    int*    gstart = (int*)   take((size_t)(NCB + 1) * 4);
    int*    gcur   = (int*)   take((size_t)NCB * 4);
    uint*   packed = (uint*)  take((size_t)EE * 4);
    int*    off    = (int*)   take((size_t)(NB + 1) * 4);
    int*    srcs   = (int*)   take((size_t)EE * 4);
    ushort* xb     = (ushort*)take((size_t)NN * 128 * 2);
    ushort* h1     = (ushort*)take((size_t)NN * 128 * 2);
    ushort* tbuf   = (ushort*)take((size_t)NN * 1152 * 2);   // 115.2 MB, reused
    ushort* Bt1    = (ushort*)take((size_t)1152 * 128 * 2);
    ushort* Bt2    = (ushort*)take((size_t)1152 * 128 * 2);
    (void)ws_size; (void)n_in; (void)in_sizes; (void)out_size;

    const int wblocks = (NN + 3) / 4;               // 12500 wave-per-node
    const dim3 tgrid(9, (NN + 63) / 64);            // 9 col-tiles x 782 row-tiles

    hipMemsetAsync(ghist, 0, (size_t)NCB * 4, stream);
    chist_kernel<<<PBLK, 1024, 0, stream>>>(dst, ghist);
    cscan_kernel<<<1, 256, 0, stream>>>(ghist, gstart, gcur);
    cpart_kernel<<<PBLK, 1024, 0, stream>>>(src, dst, etype, gcur, packed);
    fsort_kernel<<<NCB, 1024, 0, stream>>>(gstart, packed, off, srcs);
    prep_w_kernel<<<dim3(1152, 2), 128, 0, stream>>>(root1, W1, root2, W2, Bt1, Bt2);
    cvt_x_kernel <<<3125, 256, 0, stream>>>(x, xb);

    // layer 1: t = xb @ Bt1^T (+b1 on base slice); h1 = finish(t)
    gemm_t<<<tgrid, 256, 0, stream>>>(xb, Bt1, b1, tbuf);
    finish_kernel<<<wblocks, 256, 0, stream>>>(tbuf, off, srcs,
                                               nullptr, nullptr, h1, nullptr);
    // layer 2: t = h1 @ Bt2^T (+b2); out = finish(t) with fused head
    gemm_t<<<tgrid, 256, 0, stream>>>(h1, Bt2, b2, tbuf);
    finish_kernel<<<wblocks, 256, 0, stream>>>(tbuf, off, srcs,
                                               Wout, bout, nullptr, out);
}

// Round 13
// 201.986 us; speedup vs baseline: 1.3304x; 1.3304x over previous
//
#include <hip/hip_runtime.h>
#include <hip/hip_bf16.h>

// RGCN regression: N=50000, E=800000, R=8, C=H=128.
// Round 13: REVERT to R11 (204us best: R6 sort + R5 agg + R6 gemm + fused head;
// R12's transform-first moved traffic into a bigger 115MB intermediate, 269us).
// One change vs R11: agg fully software-pipelined — srcs index prefetched 2
// ahead, feature ROW prefetched 1 ahead into regs, so both loads issue before
// the previous row's accumulate (row-load latency hides under 32 VALU ops).

constexpr int NN = 50000;
constexpr int EE = 800000;
constexpr int NB = NN * 8;            // 400000 (dst,rel) buckets
constexpr int NCB = (NN + 255) >> 8;  // 196 coarse buckets
constexpr int EPB = 8192;             // edges per partition block
constexpr int PBLK = (EE + EPB - 1) / EPB;   // 98
constexpr int NSB = 2048;             // sub-buckets per coarse bucket

typedef __attribute__((ext_vector_type(8))) short bf16x8;
typedef __attribute__((ext_vector_type(16))) float f32x16;
typedef __attribute__((address_space(3))) uint32_t lds_u32;
typedef __attribute__((address_space(1))) const uint32_t glb_u32;

static __device__ __forceinline__ ushort f2bf(float f) {
    uint u = __float_as_uint(f);
    uint r = (u + 0x7fffu + ((u >> 16) & 1u)) >> 16;   // RTNE
    return (ushort)r;
}
static __device__ __forceinline__ float bflo(uint v) { return __uint_as_float(v << 16); }
static __device__ __forceinline__ float bfhi(uint v) { return __uint_as_float(v & 0xffff0000u); }

static __device__ __forceinline__ void stage16(const void* g, void* lds) {
    __builtin_amdgcn_global_load_lds((glb_u32*)g, (lds_u32*)lds, 16, 0, 0);
}

// ---------------- P1: coarse histogram (dst>>8), LDS-aggregated ----------------
__global__ __launch_bounds__(1024) void chist_kernel(const int* __restrict__ dst,
                                                     int* __restrict__ ghist) {
    __shared__ int h[NCB];
    const int t = threadIdx.x;
    for (int i = t; i < NCB; i += 1024) h[i] = 0;
    __syncthreads();
    const int e0 = blockIdx.x * EPB + t;
#pragma unroll
    for (int jj = 0; jj < 8; ++jj) {
        const int e = e0 + jj * 1024;
        if (e < EE) atomicAdd(&h[dst[e] >> 8], 1);
    }
    __syncthreads();
    for (int i = t; i < NCB; i += 1024)
        if (h[i]) atomicAdd(&ghist[i], h[i]);
}

// ---------------- P2: scan 196 coarse totals ----------------
__global__ __launch_bounds__(256) void cscan_kernel(const int* __restrict__ ghist,
                                                    int* __restrict__ gstart,
                                                    int* __restrict__ gcur) {
    __shared__ int sm[256];
    const int t = threadIdx.x;
    const int v = (t < NCB) ? ghist[t] : 0;
    sm[t] = v;
    __syncthreads();
    for (int d = 1; d < 256; d <<= 1) {
        int u = (t >= d) ? sm[t - d] : 0;
        __syncthreads();
        sm[t] += u;
        __syncthreads();
    }
    const int excl = sm[t] - v;
    if (t < NCB) { gstart[t] = excl; gcur[t] = excl; }
    if (t == NCB - 1) gstart[NCB] = excl + v;   // == EE
}

// ---------------- P3: coarse partition, block-reserved ranges ----------------
// packed = (dlow<<19) | (et<<16) | src
__global__ __launch_bounds__(1024) void cpart_kernel(const int* __restrict__ src,
                                                     const int* __restrict__ dst,
                                                     const int* __restrict__ et,
                                                     int* __restrict__ gcur,
                                                     uint* __restrict__ packed) {
    __shared__ int h[NCB];
    const int t = threadIdx.x;
    for (int i = t; i < NCB; i += 1024) h[i] = 0;
    __syncthreads();
    const int e0 = blockIdx.x * EPB + t;
    int myb[8]; uint mydat[8];
#pragma unroll
    for (int jj = 0; jj < 8; ++jj) {
        const int e = e0 + jj * 1024;
        if (e < EE) {
            const int d = dst[e];
            myb[jj] = d >> 8;
            mydat[jj] = (uint)src[e] | ((uint)et[e] << 16) | ((uint)(d & 255) << 19);
            atomicAdd(&h[myb[jj]], 1);
        } else myb[jj] = -1;
    }
    __syncthreads();
    for (int i = t; i < NCB; i += 1024)
        h[i] = h[i] ? atomicAdd(&gcur[i], h[i]) : 0;   // h becomes running cursor
    __syncthreads();
#pragma unroll
    for (int jj = 0; jj < 8; ++jj) {
        if (myb[jj] >= 0) {
            const int pos = atomicAdd(&h[myb[jj]], 1);
            packed[pos] = mydat[jj];
        }
    }
}

// ---------------- P4: per-coarse-bucket fine sort -> off[] + srcs[] ----------------
__global__ __launch_bounds__(1024) void fsort_kernel(const int* __restrict__ gstart,
                                                     const uint* __restrict__ packed,
                                                     int* __restrict__ off,
                                                     int* __restrict__ srcs) {
    __shared__ int hist[NSB];
    __shared__ int scn[NSB];
    __shared__ int h2[1024];
    const int b = blockIdx.x;
    const int t = threadIdx.x;
    const int s = gstart[b], e = gstart[b + 1];

    for (int i = t; i < NSB; i += 1024) hist[i] = 0;
    __syncthreads();
    for (int i = s + t; i < e; i += 1024)
        atomicAdd(&hist[(packed[i] >> 16) & 0x7FF], 1);
    __syncthreads();
    const int a0 = hist[2 * t], a1 = hist[2 * t + 1];
    h2[t] = a0 + a1;
    __syncthreads();
    for (int d = 1; d < 1024; d <<= 1) {
        int u = (t >= d) ? h2[t - d] : 0;
        __syncthreads();
        h2[t] += u;
        __syncthreads();
    }
    const int base = h2[t] - (a0 + a1);
    scn[2 * t] = base;
    scn[2 * t + 1] = base + a0;
    __syncthreads();
    const int gsubbase = b << 11;
    for (int i = t; i < NSB; i += 1024) {
        const int g = gsubbase + i;
        if (g < NB) off[g] = s + scn[i];
    }
    if (b == NCB - 1 && t == 0) off[NB] = EE;
    __syncthreads();
    for (int i = s + t; i < e; i += 1024) {
        const uint k = packed[i];
        const int pos = atomicAdd(&scn[(k >> 16) & 0x7FF], 1);
        srcs[s + pos] = (int)(k & 0xFFFF);
    }
}

// ---------------- x fp32 -> bf16 ----------------
__global__ __launch_bounds__(256) void cvt_x_kernel(const float* __restrict__ x,
                                                    ushort* __restrict__ xb) {
    const int tid = blockIdx.x * blockDim.x + threadIdx.x;
    const size_t i = (size_t)tid * 8;
    const float4 v0 = *reinterpret_cast<const float4*>(x + i);
    const float4 v1 = *reinterpret_cast<const float4*>(x + i + 4);
    uint4 o;
    o.x = (uint)f2bf(v0.x) | ((uint)f2bf(v0.y) << 16);
    o.y = (uint)f2bf(v0.z) | ((uint)f2bf(v0.w) << 16);
    o.z = (uint)f2bf(v1.x) | ((uint)f2bf(v1.y) << 16);
    o.w = (uint)f2bf(v1.z) | ((uint)f2bf(v1.w) << 16);
    *reinterpret_cast<uint4*>(xb + i) = o;
}

// ---------------- weights -> Bt[n][k] bf16, k = [root(128) | W(1024)] ----------------
__global__ __launch_bounds__(256) void prep_w_kernel(const float* __restrict__ root1,
                                                     const float* __restrict__ W1,
                                                     const float* __restrict__ root2,
                                                     const float* __restrict__ W2,
                                                     ushort* __restrict__ Bt1,
                                                     ushort* __restrict__ Bt2) {
    const float* root = blockIdx.y ? root2 : root1;
    const float* W    = blockIdx.y ? W2 : W1;
    ushort* Bt        = blockIdx.y ? Bt2 : Bt1;
    const int n = blockIdx.x;
    for (int k = threadIdx.x; k < 1152; k += 256) {
        float v = (k < 128) ? root[(size_t)k * 128 + n]
                            : W[(size_t)(k - 128) * 128 + n];
        Bt[(size_t)n * 1152 + k] = f2bf(v);
    }
}

// ---------------- aggregation: wave per node, 8 segments parallel, PIPELINED ----
// lane = g*8 + j. Index prefetch 2 ahead; feature-row prefetch 1 ahead, so the
// next row's 2x dwordx4 issue BEFORE this row's 32-op accumulate.
__global__ __launch_bounds__(256) void agg_kernel(const int* __restrict__ off,
                                                  const int* __restrict__ srcs,
                                                  const ushort* __restrict__ feat,
                                                  ushort* __restrict__ agg) {
    const int wid = (blockIdx.x * blockDim.x + threadIdx.x) >> 6;
    if (wid >= NN) return;
    const int lane = threadIdx.x & 63;
    const int g = lane >> 3;            // relation group 0..7
    const int j = lane & 7;             // 16-ushort chunk within row

    const int s1 = off[wid * 8 + g + 1];
    int i = off[wid * 8 + g];
    const int cnt = s1 - i;

    float a[16];
#pragma unroll
    for (int k = 0; k < 16; ++k) a[k] = 0.f;

    const size_t jb = (size_t)(j << 4);
    int p  = (i < s1)     ? srcs[i]     : 0;
    int pn = (i + 1 < s1) ? srcs[i + 1] : 0;
    const uint4* rp = reinterpret_cast<const uint4*>(feat + (size_t)p * 128 + jb);
    uint4 v0 = rp[0], v1 = rp[1];       // current row (lanes with empty seg read row 0: harmless)

    while (__any(i < s1)) {
        const int pnn = (i + 2 < s1) ? srcs[i + 2] : 0;     // index prefetch, 2 ahead
        const uint4* rn = reinterpret_cast<const uint4*>(feat + (size_t)pn * 128 + jb);
        const uint4 w0 = rn[0], w1 = rn[1];                 // row prefetch, 1 ahead
        if (i < s1) {
            a[0] += bflo(v0.x);  a[1] += bfhi(v0.x);
            a[2] += bflo(v0.y);  a[3] += bfhi(v0.y);
            a[4] += bflo(v0.z);  a[5] += bfhi(v0.z);
            a[6] += bflo(v0.w);  a[7] += bfhi(v0.w);
            a[8] += bflo(v1.x);  a[9] += bfhi(v1.x);
            a[10] += bflo(v1.y); a[11] += bfhi(v1.y);
            a[12] += bflo(v1.z); a[13] += bfhi(v1.z);
            a[14] += bflo(v1.w); a[15] += bfhi(v1.w);
        }
        v0 = w0; v1 = w1;
        p = pn; pn = pnn;
        ++i;
    }

    const float inv = 1.0f / (float)max(cnt, 1);
    uint4 o0, o1;
    o0.x = (uint)f2bf(a[0] * inv)  | ((uint)f2bf(a[1] * inv)  << 16);
    o0.y = (uint)f2bf(a[2] * inv)  | ((uint)f2bf(a[3] * inv)  << 16);
    o0.z = (uint)f2bf(a[4] * inv)  | ((uint)f2bf(a[5] * inv)  << 16);
    o0.w = (uint)f2bf(a[6] * inv)  | ((uint)f2bf(a[7] * inv)  << 16);
    o1.x = (uint)f2bf(a[8] * inv)  | ((uint)f2bf(a[9] * inv)  << 16);
    o1.y = (uint)f2bf(a[10] * inv) | ((uint)f2bf(a[11] * inv) << 16);
    o1.z = (uint)f2bf(a[12] * inv) | ((uint)f2bf(a[13] * inv) << 16);
    o1.w = (uint)f2bf(a[14] * inv) | ((uint)f2bf(a[15] * inv) << 16);
    ushort* o = agg + (size_t)wid * 1024 + g * 128 + (j << 4);
    reinterpret_cast<uint4*>(o)[0] = o0;
    reinterpret_cast<uint4*>(o)[1] = o1;
}

// ---------------- MFMA GEMM: h = relu(bias + [xb|agg] @ Bt^T) ----------------
// A logical [N, 1152] bf16, Bt [128][1152] bf16. Block: 4 waves (2x2),
// tile 64(M) x 128(N), BK=64, 2-phase dbuf (R6, measured best).
// If outp != nullptr (layer 2): fused head — out[n] = relu(h[n]).Wout + bout
// computed from fp32 accs (shfl butterfly over col-lanes + LDS cross-wave add);
// hout is not written.
__global__ __launch_bounds__(256) void gemm_mfma(const ushort* __restrict__ xb,
                                                 const ushort* __restrict__ agg,
                                                 const ushort* __restrict__ Bt,
                                                 const float* __restrict__ bias,
                                                 ushort* __restrict__ hout,
                                                 const float* __restrict__ Wout,
                                                 const float* __restrict__ bout,
                                                 float* __restrict__ outp) {
    __shared__ __align__(16) uint8_t smem[49152];
    const int t = threadIdx.x;
    const int lane = t & 63;
    const int w = t >> 6;
    const int wr = w >> 1, wc = w & 1;
    const int n0 = blockIdx.x * 64;
    const int l31 = lane & 31;
    const int lhalf = lane >> 5;

    f32x16 acc0, acc1;
#pragma unroll
    for (int r = 0; r < 16; ++r) { acc0[r] = 0.f; acc1[r] = 0.f; }

    const int rA = wr * 32 + l31;
    const int aoff = rA * 128, aswz = (rA & 7) << 4;
    const int nB0 = wc * 64 + l31;
    const int nB1 = nB0 + 32;
    const int boff0 = 8192 + nB0 * 128, bswz0 = (nB0 & 7) << 4;
    const int boff1 = 8192 + nB1 * 128, bswz1 = (nB1 & 7) << 4;
    const int ckb = lhalf << 4;

    const int rsub = lane >> 3;
    const int srcChunk = (((lane & 7) ^ (lane >> 3)) << 4);
    int garowA[2];
#pragma unroll
    for (int jj = 0; jj < 2; ++jj)
        garowA[jj] = min(n0 + 16 * w + 8 * jj + rsub, NN - 1);
    size_t bOffG[4];
#pragma unroll
    for (int jj = 0; jj < 4; ++jj)
        bOffG[jj] = (size_t)(32 * w + 8 * jj + rsub) * 2304 + srcChunk;

    const uint8_t* xb8  = (const uint8_t*)xb;
    const uint8_t* agg8 = (const uint8_t*)agg;
    const uint8_t* Bt8  = (const uint8_t*)Bt;

    auto STAGE = [&](int buf, int kt) {
        uint8_t* base = smem + buf * 24576;
        const uint8_t* Asrc; int shift, koffB;
        if (kt < 2) { Asrc = xb8;  shift = 8;  koffB = kt * 128; }
        else        { Asrc = agg8; shift = 11; koffB = (kt - 2) * 128; }
#pragma unroll
        for (int jj = 0; jj < 2; ++jj)
            stage16(Asrc + (((size_t)garowA[jj]) << shift) + koffB + srcChunk,
                    base + (2 * w + jj) * 1024);
#pragma unroll
        for (int jj = 0; jj < 4; ++jj)
            stage16(Bt8 + bOffG[jj] + kt * 128,
                    base + 8192 + (4 * w + jj) * 1024);
    };

    auto COMPUTE = [&](int buf) {
        const uint8_t* base = smem + buf * 24576;
#pragma unroll
        for (int kb = 0; kb < 4; ++kb) {
            const int cb = kb * 32 + ckb;
            const bf16x8 af = *reinterpret_cast<const bf16x8*>(base + aoff  + (cb ^ aswz));
            const bf16x8 b0 = *reinterpret_cast<const bf16x8*>(base + boff0 + (cb ^ bswz0));
            const bf16x8 b1 = *reinterpret_cast<const bf16x8*>(base + boff1 + (cb ^ bswz1));
            acc0 = __builtin_amdgcn_mfma_f32_32x32x16_bf16(af, b0, acc0, 0, 0, 0);
            acc1 = __builtin_amdgcn_mfma_f32_32x32x16_bf16(af, b1, acc1, 0, 0, 0);
        }
    };

    STAGE(0, 0);
    __syncthreads();
    int cur = 0;
#pragma unroll 1
    for (int kt = 0; kt < 17; ++kt) {
        STAGE(cur ^ 1, kt + 1);
        COMPUTE(cur);
        __syncthreads();
        cur ^= 1;
    }
    COMPUTE(cur);

    if (outp == nullptr) {
        // ---- layer 1 epilogue: write bf16 h ----
#pragma unroll
        for (int ni = 0; ni < 2; ++ni) {
            const int col = wc * 64 + ni * 32 + l31;
            const float bv = bias[col];
            const f32x16& a = ni ? acc1 : acc0;
#pragma unroll
            for (int reg = 0; reg < 16; ++reg) {
                const int row = n0 + wr * 32 + 4 * lhalf + (reg & 3) + 8 * (reg >> 2);
                if (row < NN) {
                    const float v = fmaxf(a[reg] + bv, 0.f);
                    hout[(size_t)row * 128 + col] = f2bf(v);
                }
            }
        }
    } else {
        // ---- layer 2 epilogue: fused head out[n] = relu(h).Wout + bout ----
        const int col0 = wc * 64 + l31;
        const int col1 = col0 + 32;
        const float bv0 = bias[col0], bv1 = bias[col1];
        const float wo0 = Wout[col0], wo1 = Wout[col1];
        float part[16];
#pragma unroll
        for (int reg = 0; reg < 16; ++reg) {
            part[reg] = fmaxf(acc0[reg] + bv0, 0.f) * wo0
                      + fmaxf(acc1[reg] + bv1, 0.f) * wo1;
            // butterfly over the 32 col-lanes (masks <32 stay within each half)
#pragma unroll
            for (int m = 16; m > 0; m >>= 1)
                part[reg] += __shfl_xor(part[reg], m, 64);
        }
        __syncthreads();                        // smem free for reuse
        float* hsum = (float*)smem;             // [2][64]
        if (l31 == 0) {
#pragma unroll
            for (int reg = 0; reg < 16; ++reg) {
                const int rl = wr * 32 + 4 * lhalf + (reg & 3) + 8 * (reg >> 2);
                hsum[wc * 64 + rl] = part[reg];
            }
        }
        __syncthreads();
        if (t < 64) {
            const int row = n0 + t;
            if (row < NN) outp[row] = hsum[t] + hsum[64 + t] + bout[0];
        }
    }
}

extern "C" void kernel_launch(void* const* d_in, const int* in_sizes, int n_in,
                              void* d_out, int out_size, void* d_ws, size_t ws_size,
                              hipStream_t stream) {
    const float* x     = (const float*)d_in[0];
    const int*   eidx  = (const int*)  d_in[1];
    const int*   etype = (const int*)  d_in[2];
    const float* W1    = (const float*)d_in[3];
    const float* root1 = (const float*)d_in[4];
    const float* b1    = (const float*)d_in[5];
    const float* W2    = (const float*)d_in[6];
    const float* root2 = (const float*)d_in[7];
    const float* b2    = (const float*)d_in[8];
    const float* Wout  = (const float*)d_in[9];
    const float* bout  = (const float*)d_in[10];
    float* out = (float*)d_out;

    const int* src = eidx;
    const int* dst = eidx + EE;

    char* ws = (char*)d_ws;
    size_t pos = 0;
    auto take = [&](size_t bytes) {
        char* p = ws + pos;
        pos = (pos + bytes + 255) & ~(size_t)255;
        return p;
    };
    int*    ghist  = (int*)   take((size_t)NCB * 4);
    int*    gstart = (int*)   take((size_t)(NCB + 1) * 4);
    int*    gcur   = (int*)   take((size_t)NCB * 4);
    uint*   packed = (uint*)  take((size_t)EE * 4);
    int*    off    = (int*)   take((size_t)(NB + 1) * 4);
    int*    srcs   = (int*)   take((size_t)EE * 4);
    ushort* xb     = (ushort*)take((size_t)NN * 128 * 2);
    ushort* h1     = (ushort*)take((size_t)NN * 128 * 2);
    ushort* agg    = (ushort*)take((size_t)NN * 1024 * 2);
    ushort* Bt1    = (ushort*)take((size_t)128 * 1152 * 2);
    ushort* Bt2    = (ushort*)take((size_t)128 * 1152 * 2);
    (void)ws_size; (void)n_in; (void)in_sizes; (void)out_size;

    const int wblocks = (NN + 3) / 4;               // 12500 wave-per-node
    const int gblocks = (NN + 63) / 64;             // 782 GEMM tiles

    hipMemsetAsync(ghist, 0, (size_t)NCB * 4, stream);
    chist_kernel<<<PBLK, 1024, 0, stream>>>(dst, ghist);
    cscan_kernel<<<1, 256, 0, stream>>>(ghist, gstart, gcur);
    cpart_kernel<<<PBLK, 1024, 0, stream>>>(src, dst, etype, gcur, packed);
    fsort_kernel<<<NCB, 1024, 0, stream>>>(gstart, packed, off, srcs);
    prep_w_kernel<<<dim3(128, 2), 256, 0, stream>>>(root1, W1, root2, W2, Bt1, Bt2);
    cvt_x_kernel <<<3125, 256, 0, stream>>>(x, xb);

    // layer 1
    agg_kernel<<<wblocks, 256, 0, stream>>>(off, srcs, xb, agg);
    gemm_mfma <<<gblocks, 256, 0, stream>>>(xb, agg, Bt1, b1, h1,
                                            nullptr, nullptr, nullptr);
    // layer 2 (+ fused head)
    agg_kernel<<<wblocks, 256, 0, stream>>>(off, srcs, h1, agg);
    gemm_mfma <<<gblocks, 256, 0, stream>>>(h1, agg, Bt2, b2, nullptr,
                                            Wout, bout, out);
}

// Round 15
// 201.934 us; speedup vs baseline: 1.3308x; 1.0003x over previous
//
#include <hip/hip_runtime.h>
#include <hip/hip_bf16.h>

// RGCN regression: N=50000, E=800000, R=8, C=H=128.
// Round 15: EXACT REVERT to R13 (202us best, absmax 0.0078). R14's
// fdot2_f32_bf16 "optimization" silently miscompiled on gfx950 (__has_builtin
// does not imply target support) -> absmax 1.84. No other changes this round.
//  1) 2-level MSD partition sort by (dst,rel)
//  2) cvt x -> bf16; weights -> Bt[n][k] bf16
//  3) per layer: wave-per-node agg, 8 rel-groups x 8 lanes, row-pipelined
//  4) layer1 gemm -> h1; layer2 gemm -> out (fused head from fp32 accs)

constexpr int NN = 50000;
constexpr int EE = 800000;
constexpr int NB = NN * 8;            // 400000 (dst,rel) buckets
constexpr int NCB = (NN + 255) >> 8;  // 196 coarse buckets
constexpr int EPB = 8192;             // edges per partition block
constexpr int PBLK = (EE + EPB - 1) / EPB;   // 98
constexpr int NSB = 2048;             // sub-buckets per coarse bucket

typedef __attribute__((ext_vector_type(8))) short bf16x8;
typedef __attribute__((ext_vector_type(16))) float f32x16;
typedef __attribute__((address_space(3))) uint32_t lds_u32;
typedef __attribute__((address_space(1))) const uint32_t glb_u32;

static __device__ __forceinline__ ushort f2bf(float f) {
    uint u = __float_as_uint(f);
    uint r = (u + 0x7fffu + ((u >> 16) & 1u)) >> 16;   // RTNE
    return (ushort)r;
}
static __device__ __forceinline__ float bflo(uint v) { return __uint_as_float(v << 16); }
static __device__ __forceinline__ float bfhi(uint v) { return __uint_as_float(v & 0xffff0000u); }

static __device__ __forceinline__ void stage16(const void* g, void* lds) {
    __builtin_amdgcn_global_load_lds((glb_u32*)g, (lds_u32*)lds, 16, 0, 0);
}

// ---------------- P1: coarse histogram (dst>>8), LDS-aggregated ----------------
__global__ __launch_bounds__(1024) void chist_kernel(const int* __restrict__ dst,
                                                     int* __restrict__ ghist) {
    __shared__ int h[NCB];
    const int t = threadIdx.x;
    for (int i = t; i < NCB; i += 1024) h[i] = 0;
    __syncthreads();
    const int e0 = blockIdx.x * EPB + t;
#pragma unroll
    for (int jj = 0; jj < 8; ++jj) {
        const int e = e0 + jj * 1024;
        if (e < EE) atomicAdd(&h[dst[e] >> 8], 1);
    }
    __syncthreads();
    for (int i = t; i < NCB; i += 1024)
        if (h[i]) atomicAdd(&ghist[i], h[i]);
}

// ---------------- P2: scan 196 coarse totals ----------------
__global__ __launch_bounds__(256) void cscan_kernel(const int* __restrict__ ghist,
                                                    int* __restrict__ gstart,
                                                    int* __restrict__ gcur) {
    __shared__ int sm[256];
    const int t = threadIdx.x;
    const int v = (t < NCB) ? ghist[t] : 0;
    sm[t] = v;
    __syncthreads();
    for (int d = 1; d < 256; d <<= 1) {
        int u = (t >= d) ? sm[t - d] : 0;
        __syncthreads();
        sm[t] += u;
        __syncthreads();
    }
    const int excl = sm[t] - v;
    if (t < NCB) { gstart[t] = excl; gcur[t] = excl; }
    if (t == NCB - 1) gstart[NCB] = excl + v;   // == EE
}

// ---------------- P3: coarse partition, block-reserved ranges ----------------
// packed = (dlow<<19) | (et<<16) | src
__global__ __launch_bounds__(1024) void cpart_kernel(const int* __restrict__ src,
                                                     const int* __restrict__ dst,
                                                     const int* __restrict__ et,
                                                     int* __restrict__ gcur,
                                                     uint* __restrict__ packed) {
    __shared__ int h[NCB];
    const int t = threadIdx.x;
    for (int i = t; i < NCB; i += 1024) h[i] = 0;
    __syncthreads();
    const int e0 = blockIdx.x * EPB + t;
    int myb[8]; uint mydat[8];
#pragma unroll
    for (int jj = 0; jj < 8; ++jj) {
        const int e = e0 + jj * 1024;
        if (e < EE) {
            const int d = dst[e];
            myb[jj] = d >> 8;
            mydat[jj] = (uint)src[e] | ((uint)et[e] << 16) | ((uint)(d & 255) << 19);
            atomicAdd(&h[myb[jj]], 1);
        } else myb[jj] = -1;
    }
    __syncthreads();
    for (int i = t; i < NCB; i += 1024)
        h[i] = h[i] ? atomicAdd(&gcur[i], h[i]) : 0;   // h becomes running cursor
    __syncthreads();
#pragma unroll
    for (int jj = 0; jj < 8; ++jj) {
        if (myb[jj] >= 0) {
            const int pos = atomicAdd(&h[myb[jj]], 1);
            packed[pos] = mydat[jj];
        }
    }
}

// ---------------- P4: per-coarse-bucket fine sort -> off[] + srcs[] ----------------
__global__ __launch_bounds__(1024) void fsort_kernel(const int* __restrict__ gstart,
                                                     const uint* __restrict__ packed,
                                                     int* __restrict__ off,
                                                     int* __restrict__ srcs) {
    __shared__ int hist[NSB];
    __shared__ int scn[NSB];
    __shared__ int h2[1024];
    const int b = blockIdx.x;
    const int t = threadIdx.x;
    const int s = gstart[b], e = gstart[b + 1];

    for (int i = t; i < NSB; i += 1024) hist[i] = 0;
    __syncthreads();
    for (int i = s + t; i < e; i += 1024)
        atomicAdd(&hist[(packed[i] >> 16) & 0x7FF], 1);
    __syncthreads();
    const int a0 = hist[2 * t], a1 = hist[2 * t + 1];
    h2[t] = a0 + a1;
    __syncthreads();
    for (int d = 1; d < 1024; d <<= 1) {
        int u = (t >= d) ? h2[t - d] : 0;
        __syncthreads();
        h2[t] += u;
        __syncthreads();
    }
    const int base = h2[t] - (a0 + a1);
    scn[2 * t] = base;
    scn[2 * t + 1] = base + a0;
    __syncthreads();
    const int gsubbase = b << 11;
    for (int i = t; i < NSB; i += 1024) {
        const int g = gsubbase + i;
        if (g < NB) off[g] = s + scn[i];
    }
    if (b == NCB - 1 && t == 0) off[NB] = EE;
    __syncthreads();
    for (int i = s + t; i < e; i += 1024) {
        const uint k = packed[i];
        const int pos = atomicAdd(&scn[(k >> 16) & 0x7FF], 1);
        srcs[s + pos] = (int)(k & 0xFFFF);
    }
}

// ---------------- x fp32 -> bf16 ----------------
__global__ __launch_bounds__(256) void cvt_x_kernel(const float* __restrict__ x,
                                                    ushort* __restrict__ xb) {
    const int tid = blockIdx.x * blockDim.x + threadIdx.x;
    const size_t i = (size_t)tid * 8;
    const float4 v0 = *reinterpret_cast<const float4*>(x + i);
    const float4 v1 = *reinterpret_cast<const float4*>(x + i + 4);
    uint4 o;
    o.x = (uint)f2bf(v0.x) | ((uint)f2bf(v0.y) << 16);
    o.y = (uint)f2bf(v0.z) | ((uint)f2bf(v0.w) << 16);
    o.z = (uint)f2bf(v1.x) | ((uint)f2bf(v1.y) << 16);
    o.w = (uint)f2bf(v1.z) | ((uint)f2bf(v1.w) << 16);
    *reinterpret_cast<uint4*>(xb + i) = o;
}

// ---------------- weights -> Bt[n][k] bf16, k = [root(128) | W(1024)] ----------------
__global__ __launch_bounds__(256) void prep_w_kernel(const float* __restrict__ root1,
                                                     const float* __restrict__ W1,
                                                     const float* __restrict__ root2,
                                                     const float* __restrict__ W2,
                                                     ushort* __restrict__ Bt1,
                                                     ushort* __restrict__ Bt2) {
    const float* root = blockIdx.y ? root2 : root1;
    const float* W    = blockIdx.y ? W2 : W1;
    ushort* Bt        = blockIdx.y ? Bt2 : Bt1;
    const int n = blockIdx.x;
    for (int k = threadIdx.x; k < 1152; k += 256) {
        float v = (k < 128) ? root[(size_t)k * 128 + n]
                            : W[(size_t)(k - 128) * 128 + n];
        Bt[(size_t)n * 1152 + k] = f2bf(v);
    }
}

// ---------------- aggregation: wave per node, 8 segments parallel, PIPELINED ----
// lane = g*8 + j. Index prefetch 2 ahead; feature-row prefetch 1 ahead, so the
// next row's 2x dwordx4 issue BEFORE this row's 32-op accumulate.
__global__ __launch_bounds__(256) void agg_kernel(const int* __restrict__ off,
                                                  const int* __restrict__ srcs,
                                                  const ushort* __restrict__ feat,
                                                  ushort* __restrict__ agg) {
    const int wid = (blockIdx.x * blockDim.x + threadIdx.x) >> 6;
    if (wid >= NN) return;
    const int lane = threadIdx.x & 63;
    const int g = lane >> 3;            // relation group 0..7
    const int j = lane & 7;             // 16-ushort chunk within row

    const int s1 = off[wid * 8 + g + 1];
    int i = off[wid * 8 + g];
    const int cnt = s1 - i;

    float a[16];
#pragma unroll
    for (int k = 0; k < 16; ++k) a[k] = 0.f;

    const size_t jb = (size_t)(j << 4);
    int p  = (i < s1)     ? srcs[i]     : 0;
    int pn = (i + 1 < s1) ? srcs[i + 1] : 0;
    const uint4* rp = reinterpret_cast<const uint4*>(feat + (size_t)p * 128 + jb);
    uint4 v0 = rp[0], v1 = rp[1];       // current row (empty-seg lanes read row 0: harmless)

    while (__any(i < s1)) {
        const int pnn = (i + 2 < s1) ? srcs[i + 2] : 0;     // index prefetch, 2 ahead
        const uint4* rn = reinterpret_cast<const uint4*>(feat + (size_t)pn * 128 + jb);
        const uint4 w0 = rn[0], w1 = rn[1];                 // row prefetch, 1 ahead
        if (i < s1) {
            a[0] += bflo(v0.x);  a[1] += bfhi(v0.x);
            a[2] += bflo(v0.y);  a[3] += bfhi(v0.y);
            a[4] += bflo(v0.z);  a[5] += bfhi(v0.z);
            a[6] += bflo(v0.w);  a[7] += bfhi(v0.w);
            a[8] += bflo(v1.x);  a[9] += bfhi(v1.x);
            a[10] += bflo(v1.y); a[11] += bfhi(v1.y);
            a[12] += bflo(v1.z); a[13] += bfhi(v1.z);
            a[14] += bflo(v1.w); a[15] += bfhi(v1.w);
        }
        v0 = w0; v1 = w1;
        p = pn; pn = pnn;
        ++i;
    }

    const float inv = 1.0f / (float)max(cnt, 1);
    uint4 o0, o1;
    o0.x = (uint)f2bf(a[0] * inv)  | ((uint)f2bf(a[1] * inv)  << 16);
    o0.y = (uint)f2bf(a[2] * inv)  | ((uint)f2bf(a[3] * inv)  << 16);
    o0.z = (uint)f2bf(a[4] * inv)  | ((uint)f2bf(a[5] * inv)  << 16);
    o0.w = (uint)f2bf(a[6] * inv)  | ((uint)f2bf(a[7] * inv)  << 16);
    o1.x = (uint)f2bf(a[8] * inv)  | ((uint)f2bf(a[9] * inv)  << 16);
    o1.y = (uint)f2bf(a[10] * inv) | ((uint)f2bf(a[11] * inv) << 16);
    o1.z = (uint)f2bf(a[12] * inv) | ((uint)f2bf(a[13] * inv) << 16);
    o1.w = (uint)f2bf(a[14] * inv) | ((uint)f2bf(a[15] * inv) << 16);
    ushort* o = agg + (size_t)wid * 1024 + g * 128 + (j << 4);
    reinterpret_cast<uint4*>(o)[0] = o0;
    reinterpret_cast<uint4*>(o)[1] = o1;
}

// ---------------- MFMA GEMM: h = relu(bias + [xb|agg] @ Bt^T) ----------------
// A logical [N, 1152] bf16, Bt [128][1152] bf16. Block: 4 waves (2x2),
// tile 64(M) x 128(N), BK=64, 2-phase dbuf (R6, measured best).
// If outp != nullptr (layer 2): fused head — out[n] = relu(h[n]).Wout + bout
// computed from fp32 accs (shfl butterfly + LDS cross-wave add); hout unused.
__global__ __launch_bounds__(256) void gemm_mfma(const ushort* __restrict__ xb,
                                                 const ushort* __restrict__ agg,
                                                 const ushort* __restrict__ Bt,
                                                 const float* __restrict__ bias,
                                                 ushort* __restrict__ hout,
                                                 const float* __restrict__ Wout,
                                                 const float* __restrict__ bout,
                                                 float* __restrict__ outp) {
    __shared__ __align__(16) uint8_t smem[49152];
    const int t = threadIdx.x;
    const int lane = t & 63;
    const int w = t >> 6;
    const int wr = w >> 1, wc = w & 1;
    const int n0 = blockIdx.x * 64;
    const int l31 = lane & 31;
    const int lhalf = lane >> 5;

    f32x16 acc0, acc1;
#pragma unroll
    for (int r = 0; r < 16; ++r) { acc0[r] = 0.f; acc1[r] = 0.f; }

    const int rA = wr * 32 + l31;
    const int aoff = rA * 128, aswz = (rA & 7) << 4;
    const int nB0 = wc * 64 + l31;
    const int nB1 = nB0 + 32;
    const int boff0 = 8192 + nB0 * 128, bswz0 = (nB0 & 7) << 4;
    const int boff1 = 8192 + nB1 * 128, bswz1 = (nB1 & 7) << 4;
    const int ckb = lhalf << 4;

    const int rsub = lane >> 3;
    const int srcChunk = (((lane & 7) ^ (lane >> 3)) << 4);
    int garowA[2];
#pragma unroll
    for (int jj = 0; jj < 2; ++jj)
        garowA[jj] = min(n0 + 16 * w + 8 * jj + rsub, NN - 1);
    size_t bOffG[4];
#pragma unroll
    for (int jj = 0; jj < 4; ++jj)
        bOffG[jj] = (size_t)(32 * w + 8 * jj + rsub) * 2304 + srcChunk;

    const uint8_t* xb8  = (const uint8_t*)xb;
    const uint8_t* agg8 = (const uint8_t*)agg;
    const uint8_t* Bt8  = (const uint8_t*)Bt;

    auto STAGE = [&](int buf, int kt) {
        uint8_t* base = smem + buf * 24576;
        const uint8_t* Asrc; int shift, koffB;
        if (kt < 2) { Asrc = xb8;  shift = 8;  koffB = kt * 128; }
        else        { Asrc = agg8; shift = 11; koffB = (kt - 2) * 128; }
#pragma unroll
        for (int jj = 0; jj < 2; ++jj)
            stage16(Asrc + (((size_t)garowA[jj]) << shift) + koffB + srcChunk,
                    base + (2 * w + jj) * 1024);
#pragma unroll
        for (int jj = 0; jj < 4; ++jj)
            stage16(Bt8 + bOffG[jj] + kt * 128,
                    base + 8192 + (4 * w + jj) * 1024);
    };

    auto COMPUTE = [&](int buf) {
        const uint8_t* base = smem + buf * 24576;
#pragma unroll
        for (int kb = 0; kb < 4; ++kb) {
            const int cb = kb * 32 + ckb;
            const bf16x8 af = *reinterpret_cast<const bf16x8*>(base + aoff  + (cb ^ aswz));
            const bf16x8 b0 = *reinterpret_cast<const bf16x8*>(base + boff0 + (cb ^ bswz0));
            const bf16x8 b1 = *reinterpret_cast<const bf16x8*>(base + boff1 + (cb ^ bswz1));
            acc0 = __builtin_amdgcn_mfma_f32_32x32x16_bf16(af, b0, acc0, 0, 0, 0);
            acc1 = __builtin_amdgcn_mfma_f32_32x32x16_bf16(af, b1, acc1, 0, 0, 0);
        }
    };

    STAGE(0, 0);
    __syncthreads();
    int cur = 0;
#pragma unroll 1
    for (int kt = 0; kt < 17; ++kt) {
        STAGE(cur ^ 1, kt + 1);
        COMPUTE(cur);
        __syncthreads();
        cur ^= 1;
    }
    COMPUTE(cur);

    if (outp == nullptr) {
        // ---- layer 1 epilogue: write bf16 h ----
#pragma unroll
        for (int ni = 0; ni < 2; ++ni) {
            const int col = wc * 64 + ni * 32 + l31;
            const float bv = bias[col];
            const f32x16& a = ni ? acc1 : acc0;
#pragma unroll
            for (int reg = 0; reg < 16; ++reg) {
                const int row = n0 + wr * 32 + 4 * lhalf + (reg & 3) + 8 * (reg >> 2);
                if (row < NN) {
                    const float v = fmaxf(a[reg] + bv, 0.f);
                    hout[(size_t)row * 128 + col] = f2bf(v);
                }
            }
        }
    } else {
        // ---- layer 2 epilogue: fused head out[n] = relu(h).Wout + bout ----
        const int col0 = wc * 64 + l31;
        const int col1 = col0 + 32;
        const float bv0 = bias[col0], bv1 = bias[col1];
        const float wo0 = Wout[col0], wo1 = Wout[col1];
        float part[16];
#pragma unroll
        for (int reg = 0; reg < 16; ++reg) {
            part[reg] = fmaxf(acc0[reg] + bv0, 0.f) * wo0
                      + fmaxf(acc1[reg] + bv1, 0.f) * wo1;
#pragma unroll
            for (int m = 16; m > 0; m >>= 1)
                part[reg] += __shfl_xor(part[reg], m, 64);
        }
        __syncthreads();                        // smem free for reuse
        float* hsum = (float*)smem;             // [2][64]
        if (l31 == 0) {
#pragma unroll
            for (int reg = 0; reg < 16; ++reg) {
                const int rl = wr * 32 + 4 * lhalf + (reg & 3) + 8 * (reg >> 2);
                hsum[wc * 64 + rl] = part[reg];
            }
        }
        __syncthreads();
        if (t < 64) {
            const int row = n0 + t;
            if (row < NN) outp[row] = hsum[t] + hsum[64 + t] + bout[0];
        }
    }
}

extern "C" void kernel_launch(void* const* d_in, const int* in_sizes, int n_in,
                              void* d_out, int out_size, void* d_ws, size_t ws_size,
                              hipStream_t stream) {
    const float* x     = (const float*)d_in[0];
    const int*   eidx  = (const int*)  d_in[1];
    const int*   etype = (const int*)  d_in[2];
    const float* W1    = (const float*)d_in[3];
    const float* root1 = (const float*)d_in[4];
    const float* b1    = (const float*)d_in[5];
    const float* W2    = (const float*)d_in[6];
    const float* root2 = (const float*)d_in[7];
    const float* b2    = (const float*)d_in[8];
    const float* Wout  = (const float*)d_in[9];
    const float* bout  = (const float*)d_in[10];
    float* out = (float*)d_out;

    const int* src = eidx;
    const int* dst = eidx + EE;

    char* ws = (char*)d_ws;
    size_t pos = 0;
    auto take = [&](size_t bytes) {
        char* p = ws + pos;
        pos = (pos + bytes + 255) & ~(size_t)255;
        return p;
    };
    int*    ghist  = (int*)   take((size_t)NCB * 4);
    int*    gstart = (int*)   take((size_t)(NCB + 1) * 4);
    int*    gcur   = (int*)   take((size_t)NCB * 4);
    uint*   packed = (uint*)  take((size_t)EE * 4);
    int*    off    = (int*)   take((size_t)(NB + 1) * 4);
    int*    srcs   = (int*)   take((size_t)EE * 4);
    ushort* xb     = (ushort*)take((size_t)NN * 128 * 2);
    ushort* h1     = (ushort*)take((size_t)NN * 128 * 2);
    ushort* agg    = (ushort*)take((size_t)NN * 1024 * 2);
    ushort* Bt1    = (ushort*)take((size_t)128 * 1152 * 2);
    ushort* Bt2    = (ushort*)take((size_t)128 * 1152 * 2);
    (void)ws_size; (void)n_in; (void)in_sizes; (void)out_size;

    const int wblocks = (NN + 3) / 4;               // 12500 wave-per-node
    const int gblocks = (NN + 63) / 64;             // 782 GEMM tiles

    hipMemsetAsync(ghist, 0, (size_t)NCB * 4, stream);
    chist_kernel<<<PBLK, 1024, 0, stream>>>(dst, ghist);
    cscan_kernel<<<1, 256, 0, stream>>>(ghist, gstart, gcur);
    cpart_kernel<<<PBLK, 1024, 0, stream>>>(src, dst, etype, gcur, packed);
    fsort_kernel<<<NCB, 1024, 0, stream>>>(gstart, packed, off, srcs);
    prep_w_kernel<<<dim3(128, 2), 256, 0, stream>>>(root1, W1, root2, W2, Bt1, Bt2);
    cvt_x_kernel <<<3125, 256, 0, stream>>>(x, xb);

    // layer 1
    agg_kernel<<<wblocks, 256, 0, stream>>>(off, srcs, xb, agg);
    gemm_mfma <<<gblocks, 256, 0, stream>>>(xb, agg, Bt1, b1, h1,
                                            nullptr, nullptr, nullptr);
    // layer 2 (+ fused head)
    agg_kernel<<<wblocks, 256, 0, stream>>>(off, srcs, h1, agg);
    gemm_mfma <<<gblocks, 256, 0, stream>>>(h1, agg, Bt2, b2, nullptr,
                                            Wout, bout, out);
}